// Round 7
// baseline (1302.051 us; speedup 1.0000x reference)
//
#include <hip/hip_runtime.h>

#define T_STEPS 2048
#define BATCH   128
#define HID     100     // LSTM hidden size
#define HP      112     // padded hidden length (multiple of 16)
#define NTH     448     // 7 waves of 64

typedef float F2 __attribute__((ext_vector_type(2)));

// DPP quad_perm helpers (VALU pipe, immediate ctrl)
template <int CTRL>
__device__ __forceinline__ float dpp_mov(float v) {
    int y = __builtin_amdgcn_update_dpp(0, __float_as_int(v), CTRL, 0xF, 0xF, true);
    return __int_as_float(y);
}
template <int CTRL>
__device__ __forceinline__ float dpp_add(float v) {
    return v + dpp_mov<CTRL>(v);
}

__global__ __launch_bounds__(NTH)
__attribute__((amdgpu_waves_per_eu(2, 2)))
void lstm_caviar_kernel(
    const float* __restrict__ x,      // [T, B, 1]
    const float* __restrict__ W_ih,   // [400, 1]
    const float* __restrict__ W_hh,   // [400, 100]
    const float* __restrict__ b_ih,   // [400]
    const float* __restrict__ b_hh,   // [400]
    const float* __restrict__ W1,     // [64, 100]
    const float* __restrict__ b1,     // [64]
    const float* __restrict__ W2,     // [1, 64]
    const float* __restrict__ b2,     // [1]
    float* __restrict__ out)          // [1]
{
    __shared__ __align__(16) float h_buf[2][HP];
    __shared__ float x_lds[T_STEPS];
    __shared__ float red_lds[64];

    const int tid = threadIdx.x;
    const int j   = tid >> 2;     // hidden unit owned by this quad
    const int s   = tid & 3;      // k-split / gate-specialization lane
    const bool active = (j < HID);

    // stage batch-0 inputs (x[t,0,0] = flat[t*BATCH]) into LDS once
    for (int t = tid; t < T_STEPS; t += NTH)
        x_lds[t] = x[t * BATCH];
    if (tid < HP) { h_buf[0][tid] = 0.0f; h_buf[1][tid] = 0.0f; }

    // Preload W_hh as float2 pairs: lane covers k = 16*m + 4*s + {0,1},{2,3}.
    // wi/bias pre-scaled by 0.25 so the 4-lane butterfly sums them to exactly 1x.
    F2 w2[4][14];
    float wi4[4], bs4[4];
    #pragma unroll
    for (int g = 0; g < 4; ++g) {
        const int gate = g * HID + (active ? j : 0);
        const float* row = W_hh + gate * HID;
        #pragma unroll
        for (int m = 0; m < 7; ++m) {
            #pragma unroll
            for (int p = 0; p < 2; ++p) {
                const int k0 = 16 * m + 4 * s + 2 * p;
                F2 v;
                v.x = (active && k0 + 0 < HID) ? row[k0 + 0] : 0.0f;
                v.y = (active && k0 + 1 < HID) ? row[k0 + 1] : 0.0f;
                w2[g][m * 2 + p] = v;
            }
        }
        wi4[g] = active ? 0.25f * W_ih[gate] : 0.0f;
        bs4[g] = active ? 0.25f * (b_ih[gate] + b_hh[gate]) : 0.0f;
    }

    const bool is_g = (s == 2);
    float c = 0.0f;
    __syncthreads();

    for (int t = 0; t < T_STEPS; ++t) {
        // Pin weight pairs into VGPRs every iteration (loop-carried asm ties).
        #pragma unroll
        for (int g = 0; g < 4; ++g) {
            #pragma unroll
            for (int k = 0; k < 14; ++k)
                asm volatile("" : "+v"(w2[g][k]));
            asm volatile("" : "+v"(wi4[g]), "+v"(bs4[g]));
        }

        const float* hb = h_buf[t & 1];
        const float xt = x_lds[t];

        F2 acc0 = {fmaf(wi4[0], xt, bs4[0]), 0.0f};
        F2 acc1 = {fmaf(wi4[1], xt, bs4[1]), 0.0f};
        F2 acc2 = {fmaf(wi4[2], xt, bs4[2]), 0.0f};
        F2 acc3 = {fmaf(wi4[3], xt, bs4[3]), 0.0f};

        #pragma unroll
        for (int m = 0; m < 7; ++m) {
            const float4 hv = *(const float4*)(hb + 16 * m + 4 * s);
            const F2 hlo = {hv.x, hv.y};
            const F2 hhi = {hv.z, hv.w};
            acc0 = __builtin_elementwise_fma(w2[0][m*2+0], hlo, acc0);
            acc0 = __builtin_elementwise_fma(w2[0][m*2+1], hhi, acc0);
            acc1 = __builtin_elementwise_fma(w2[1][m*2+0], hlo, acc1);
            acc1 = __builtin_elementwise_fma(w2[1][m*2+1], hhi, acc1);
            acc2 = __builtin_elementwise_fma(w2[2][m*2+0], hlo, acc2);
            acc2 = __builtin_elementwise_fma(w2[2][m*2+1], hhi, acc2);
            acc3 = __builtin_elementwise_fma(w2[3][m*2+0], hlo, acc3);
            acc3 = __builtin_elementwise_fma(w2[3][m*2+1], hhi, acc3);
        }

        // collapse pairs, then quad butterfly (DPP): all lanes get all 4 sums
        float a0 = acc0.x + acc0.y;
        float a1 = acc1.x + acc1.y;
        float a2 = acc2.x + acc2.y;
        float a3 = acc3.x + acc3.y;
        a0 = dpp_add<0xB1>(a0); a0 = dpp_add<0x4E>(a0);
        a1 = dpp_add<0xB1>(a1); a1 = dpp_add<0x4E>(a1);
        a2 = dpp_add<0xB1>(a2); a2 = dpp_add<0x4E>(a2);
        a3 = dpp_add<0xB1>(a3); a3 = dpp_add<0x4E>(a3);

        // lane s activates gate s only (i,f,o: sigmoid; g: tanh = 2*sig(2x)-1)
        const float a  = (s & 1) ? ((s & 2) ? a3 : a1)
                                 : ((s & 2) ? a2 : a0);
        const float pre = is_g ? (a + a) : a;
        const float e   = __expf(-pre);
        const float v   = 1.0f / (1.0f + e);
        const float act = is_g ? (v + v - 1.0f) : v;

        // redistribute the four activations within the quad (DPP broadcasts)
        const float ig = dpp_mov<0x00>(act);
        const float fg = dpp_mov<0x55>(act);
        const float gg = dpp_mov<0xAA>(act);
        const float og = dpp_mov<0xFF>(act);

        c = fmaf(fg, c, ig * gg);
        const float e2 = __expf(-2.0f * c);
        const float th = 2.0f / (1.0f + e2) - 1.0f;
        const float h  = og * th;

        if (active && s == 0)
            h_buf[(t + 1) & 1][j] = h;
        __syncthreads();
    }

    // head: lin = W1 @ h + b1 (64), out = W2 @ lin + b2 (scalar)
    if (tid < 64) {
        const float* r = W1 + tid * HID;
        const float* hf = h_buf[0];   // T even -> final h in buf 0
        float a = 0.0f;
        for (int k = 0; k < HID; ++k)
            a = fmaf(r[k], hf[k], a);
        red_lds[tid] = a + b1[tid];
    }
    __syncthreads();
    if (tid == 0) {
        float a = b2[0];
        for (int k = 0; k < 64; ++k)
            a = fmaf(W2[k], red_lds[k], a);
        out[0] = a;
    }
}

extern "C" void kernel_launch(void* const* d_in, const int* in_sizes, int n_in,
                              void* d_out, int out_size, void* d_ws, size_t ws_size,
                              hipStream_t stream) {
    lstm_caviar_kernel<<<1, NTH, 0, stream>>>(
        (const float*)d_in[0],  // input_seq
        (const float*)d_in[1],  // W_ih
        (const float*)d_in[2],  // W_hh
        (const float*)d_in[3],  // b_ih
        (const float*)d_in[4],  // b_hh
        (const float*)d_in[5],  // W1
        (const float*)d_in[6],  // b1
        (const float*)d_in[7],  // W2
        (const float*)d_in[8],  // b2
        (float*)d_out);
}